// Round 7
// baseline (402.210 us; speedup 1.0000x reference)
//
#include <hip/hip_runtime.h>
#include <hip/hip_bf16.h>
#include <math.h>

#define EMBED 128
#define VOCAB 32000
#define MEMN  50
#define BATCH 16
#define NQ    10
#define SQ    20
#define SS    40
#define BN    (BATCH*NQ)   // 160
#define NHOPS 3
#define NV    64           // vocab rows per k_out block

// Profiling amplification (idempotent reps; asm memory-clobber defeats hoisting)
#define EREP 16
#define HREP 24
#define OREP 10

typedef short v8s __attribute__((ext_vector_type(8)));
typedef float v4f __attribute__((ext_vector_type(4)));

__device__ __forceinline__ float posw(int j, int J, int k) {
    float jf = (float)(j + 1) / (float)J;
    return 1.0f - jf - ((float)(k + 1) / (float)EMBED) * (1.0f - 2.0f * jf);
}

__device__ __forceinline__ short f2bf(float f) {
    __hip_bfloat16 h = __float2bfloat16(f);
    return *(short*)&h;
}

// ---- Kernel 1 (R2-exact body, x EREP): query | story | H^T ----
__global__ void k_embed(const int* __restrict__ cq, const int* __restrict__ story,
                        const float* __restrict__ Bw, const float* __restrict__ Aw,
                        const float* __restrict__ Cw, const float* __restrict__ TA,
                        const float* __restrict__ TC, const float* __restrict__ Hw,
                        float* __restrict__ state, float* __restrict__ memb,
                        float* __restrict__ outb, float* __restrict__ HwT) {
    int blk = blockIdx.x;
    int t = threadIdx.x;   // 128
    for (int rep = 0; rep < EREP; ++rep) {
        asm volatile("" ::: "memory");
        if (blk < BN) {
            float acc = 0.f;
            #pragma unroll
            for (int s = 0; s < SQ; ++s) {
                int tok = cq[blk * SQ + s];
                acc += Bw[tok * EMBED + t] * posw(s, SQ, t);
            }
            state[blk * EMBED + t] = acc;
        } else if (blk < BN + BATCH * MEMN) {
            int br = blk - BN;
            int r = br % MEMN;
            float ma = TA[r * EMBED + t];
            float mc = TC[r * EMBED + t];
            const int* toks = story + br * SS;
            #pragma unroll 4
            for (int s = 0; s < SS; ++s) {
                int tok = toks[s];
                float w = posw(s, SS, t);
                ma += Aw[tok * EMBED + t] * w;
                mc += Cw[tok * EMBED + t] * w;
            }
            memb[br * EMBED + t] = ma;
            outb[br * EMBED + t] = mc;
        } else {
            int k = blk - (BN + BATCH * MEMN);
            HwT[k * EMBED + t] = Hw[t * EMBED + k];
        }
    }
}

// ---- Kernel 2 (R2-exact body, x HREP): 3 hops -> stateb bf16 ----
__global__ void k_hops(const float* __restrict__ memb, const float* __restrict__ outb,
                       const float* __restrict__ HwT, const float* __restrict__ Hb,
                       const float* __restrict__ state, __hip_bfloat16* __restrict__ stateb) {
    __shared__ float lmem[MEMN][EMBED + 1];
    __shared__ float lout[MEMN][EMBED + 1];
    __shared__ float lstate[EMBED];
    __shared__ float lprobs[MEMN];
    __shared__ float lresp[EMBED];
    int bn = blockIdx.x;
    int b  = bn / NQ;
    int t  = threadIdx.x;   // 128
    for (int rep = 0; rep < HREP; ++rep) {
        asm volatile("" ::: "memory");
        for (int i = t; i < MEMN * EMBED; i += EMBED) {
            int r = i >> 7, d = i & 127;
            lmem[r][d] = memb[b * MEMN * EMBED + i];
            lout[r][d] = outb[b * MEMN * EMBED + i];
        }
        lstate[t] = state[bn * EMBED + t];
        __syncthreads();

        for (int hop = 0; hop < NHOPS; ++hop) {
            float logit = -1e30f;
            if (t < MEMN) {
                float acc = 0.f;
                for (int d = 0; d < EMBED; ++d) acc += lmem[t][d] * lstate[d];
                logit = acc;
            }
            if (t < 64) {
                float m = logit;
                #pragma unroll
                for (int off = 32; off; off >>= 1) m = fmaxf(m, __shfl_xor(m, off, 64));
                float e = (t < MEMN) ? __expf(logit - m) : 0.f;
                float ssum = e;
                #pragma unroll
                for (int off = 32; off; off >>= 1) ssum += __shfl_xor(ssum, off, 64);
                if (t < MEMN) lprobs[t] = e / ssum;
            }
            __syncthreads();
            float resp = 0.f;
            for (int r = 0; r < MEMN; ++r) resp += lprobs[r] * lout[r][t];
            lresp[t] = resp;
            __syncthreads();
            float acc = Hb[t] + lstate[t];
            for (int k = 0; k < EMBED; ++k) acc += lresp[k] * HwT[k * EMBED + t];
            __syncthreads();
            lstate[t] = acc;
            __syncthreads();
        }
        stateb[bn * EMBED + t] = __float2bfloat16(lstate[t]);
        __syncthreads();   // protect LDS before next rep's restage
    }
}

// ---- Kernel 3 (R2-exact body, x OREP): MFMA GEMM ----
__global__ __launch_bounds__(256) void k_out(const __hip_bfloat16* __restrict__ stateb,
                                             const float* __restrict__ outw,
                                             float* __restrict__ out) {
    __shared__ __align__(16) __hip_bfloat16 Alds[BN][EMBED + 8];
    __shared__ __align__(16) __hip_bfloat16 Blds[NV][EMBED + 8];
    int t = threadIdx.x;
    int vbase = blockIdx.x * NV;
    for (int rep = 0; rep < OREP; ++rep) {
        asm volatile("" ::: "memory");
        #pragma unroll
        for (int i = 0; i < 10; ++i) {
            int e = t + i * 256;
            int row = e >> 4, c8 = (e & 15) << 3;
            *(int4*)&Alds[row][c8] = *(const int4*)&stateb[row * EMBED + c8];
        }
        #pragma unroll
        for (int i = 0; i < 8; ++i) {
            int e = t + i * 256;
            int row = e >> 5, c4 = (e & 31) << 2;
            float4 w = *(const float4*)&outw[(size_t)(vbase + row) * EMBED + c4];
            short4 p;
            p.x = f2bf(w.x); p.y = f2bf(w.y); p.z = f2bf(w.z); p.w = f2bf(w.w);
            *(short4*)&Blds[row][c4] = p;
        }
        __syncthreads();

        int wv = t >> 6;
        int l = t & 63;
        int col16 = l & 15;
        int kg = l >> 4;

        v8s bfrag[4];
        #pragma unroll
        for (int k4 = 0; k4 < 4; ++k4)
            bfrag[k4] = *(v8s*)&Blds[(wv << 4) + col16][k4 * 32 + kg * 8];

        v4f acc[10];
        #pragma unroll
        for (int m = 0; m < 10; ++m) acc[m] = (v4f){0.f, 0.f, 0.f, 0.f};

        #pragma unroll
        for (int k4 = 0; k4 < 4; ++k4) {
            #pragma unroll
            for (int m = 0; m < 10; ++m) {
                v8s af = *(v8s*)&Alds[m * 16 + col16][k4 * 32 + kg * 8];
                acc[m] = __builtin_amdgcn_mfma_f32_16x16x32_bf16(af, bfrag[k4], acc[m], 0, 0, 0);
            }
        }

        int colg = vbase + (wv << 4) + col16;
        #pragma unroll
        for (int m = 0; m < 10; ++m) {
            #pragma unroll
            for (int i = 0; i < 4; ++i) {
                out[(size_t)(m * 16 + kg * 4 + i) * VOCAB + colg] = acc[m][i];
            }
        }
        __syncthreads();   // protect LDS before next rep's restage
    }
}

extern "C" void kernel_launch(void* const* d_in, const int* in_sizes, int n_in,
                              void* d_out, int out_size, void* d_ws, size_t ws_size,
                              hipStream_t stream) {
    const int*   ctx_query = (const int*)  d_in[0];
    const int*   story     = (const int*)  d_in[1];
    const float* A_w       = (const float*)d_in[2];
    const float* C_w       = (const float*)d_in[3];
    const float* B_w       = (const float*)d_in[4];
    const float* H_w       = (const float*)d_in[5];
    const float* H_b       = (const float*)d_in[6];
    const float* out_w     = (const float*)d_in[7];
    const float* TA        = (const float*)d_in[8];
    const float* TC        = (const float*)d_in[9];
    float* out = (float*)d_out;

    float* ws    = (float*)d_ws;
    float* state = ws;                                   // 160*128 f32
    float* memb  = state + BN * EMBED;                   // 16*50*128
    float* outb  = memb + BATCH * MEMN * EMBED;          // 16*50*128
    float* HwT   = outb + BATCH * MEMN * EMBED;          // 128*128
    __hip_bfloat16* stateb = (__hip_bfloat16*)(HwT + EMBED * EMBED);  // 160*128 bf16

    k_embed<<<BN + BATCH * MEMN + EMBED, EMBED, 0, stream>>>(
        ctx_query, story, B_w, A_w, C_w, TA, TC, H_w, state, memb, outb, HwT);
    k_hops<<<BN, EMBED, 0, stream>>>(memb, outb, HwT, H_b, state, stateb);
    k_out<<<VOCAB / NV, 256, 0, stream>>>(stateb, out_w, out);
}

// Round 8
// 34.541 us; speedup vs baseline: 11.6445x; 11.6445x over previous
//
#include <hip/hip_runtime.h>
#include <hip/hip_bf16.h>
#include <math.h>

#define EMBED 128
#define VOCAB 32000
#define MEMN  50
#define BATCH 16
#define NQ    10
#define SQ    20
#define SS    40
#define BN    (BATCH*NQ)   // 160
#define NHOPS 3
#define NV    64           // vocab rows per k_out block

typedef short v8s __attribute__((ext_vector_type(8)));
typedef float v4f __attribute__((ext_vector_type(4)));

__device__ __forceinline__ float posw(int j, int J, int k) {
    float jf = (float)(j + 1) / (float)J;
    return 1.0f - jf - ((float)(k + 1) / (float)EMBED) * (1.0f - 2.0f * jf);
}

__device__ __forceinline__ short f2bf(float f) {
    __hip_bfloat16 h = __float2bfloat16(f);
    return *(short*)&h;
}

// ---- Kernel 1 (R2-exact): query | story | H^T ----
__global__ void k_embed(const int* __restrict__ cq, const int* __restrict__ story,
                        const float* __restrict__ Bw, const float* __restrict__ Aw,
                        const float* __restrict__ Cw, const float* __restrict__ TA,
                        const float* __restrict__ TC, const float* __restrict__ Hw,
                        float* __restrict__ state, float* __restrict__ memb,
                        float* __restrict__ outb, float* __restrict__ HwT) {
    int blk = blockIdx.x;
    int t = threadIdx.x;   // 128
    if (blk < BN) {
        float acc = 0.f;
        #pragma unroll
        for (int s = 0; s < SQ; ++s) {
            int tok = cq[blk * SQ + s];
            acc += Bw[tok * EMBED + t] * posw(s, SQ, t);
        }
        state[blk * EMBED + t] = acc;
    } else if (blk < BN + BATCH * MEMN) {
        int br = blk - BN;
        int r = br % MEMN;
        float ma = TA[r * EMBED + t];
        float mc = TC[r * EMBED + t];
        const int* toks = story + br * SS;
        #pragma unroll 4
        for (int s = 0; s < SS; ++s) {
            int tok = toks[s];
            float w = posw(s, SS, t);
            ma += Aw[tok * EMBED + t] * w;
            mc += Cw[tok * EMBED + t] * w;
        }
        memb[br * EMBED + t] = ma;
        outb[br * EMBED + t] = mc;
    } else {
        int k = blk - (BN + BATCH * MEMN);
        HwT[k * EMBED + t] = Hw[t * EMBED + k];
    }
}

// ---- Kernel 2 v2: 3 hops, serial chains broken (R7 counters: 12us/call,
// latency-bound on un-reassociable FMA chains). All dot products use 4
// independent accumulators; logits split-K across the 2 waves. ----
__global__ void k_hops(const float* __restrict__ memb, const float* __restrict__ outb,
                       const float* __restrict__ HwT, const float* __restrict__ Hb,
                       const float* __restrict__ state, __hip_bfloat16* __restrict__ stateb) {
    __shared__ float lmem[MEMN][EMBED + 1];   // +1 pad: (r + d) % 32 banks, conflict-free
    __shared__ float lout[MEMN][EMBED + 1];
    __shared__ float lstate[EMBED];
    __shared__ float lpart[2][64];
    __shared__ float lprobs[MEMN];
    __shared__ float lresp[EMBED];
    int bn = blockIdx.x;
    int b  = bn / NQ;
    int t  = threadIdx.x;   // 128
    int h  = t >> 6;        // wave: K-half for logits
    int r  = t & 63;        // row for logits

    // Stage batch memories: float4 global loads, scalar LDS stores (pad=1)
    {
        size_t base = (size_t)b * MEMN * EMBED;
        for (int i = t; i < MEMN * EMBED / 4; i += 128) {
            int row = i >> 5, c = (i & 31) << 2;
            float4 v = *(const float4*)&memb[base + ((size_t)i << 2)];
            lmem[row][c] = v.x; lmem[row][c + 1] = v.y;
            lmem[row][c + 2] = v.z; lmem[row][c + 3] = v.w;
            float4 w = *(const float4*)&outb[base + ((size_t)i << 2)];
            lout[row][c] = w.x; lout[row][c + 1] = w.y;
            lout[row][c + 2] = w.z; lout[row][c + 3] = w.w;
        }
        lstate[t] = state[bn * EMBED + t];
    }
    __syncthreads();

    for (int hop = 0; hop < NHOPS; ++hop) {
        // ---- logits: thread (h,r) partial-dots 64 dims, 4 accumulators ----
        if (r < MEMN) {
            float a0 = 0.f, a1 = 0.f, a2 = 0.f, a3 = 0.f;
            int d0 = h << 6;
            #pragma unroll
            for (int j = 0; j < 64; j += 4) {
                a0 += lmem[r][d0 + j]     * lstate[d0 + j];
                a1 += lmem[r][d0 + j + 1] * lstate[d0 + j + 1];
                a2 += lmem[r][d0 + j + 2] * lstate[d0 + j + 2];
                a3 += lmem[r][d0 + j + 3] * lstate[d0 + j + 3];
            }
            lpart[h][r] = (a0 + a1) + (a2 + a3);
        }
        __syncthreads();
        // ---- softmax in wave 0 ----
        if (t < 64) {
            float logit = (t < MEMN) ? lpart[0][t] + lpart[1][t] : -1e30f;
            float m = logit;
            #pragma unroll
            for (int off = 32; off; off >>= 1) m = fmaxf(m, __shfl_xor(m, off, 64));
            float e = (t < MEMN) ? __expf(logit - m) : 0.f;
            float ssum = e;
            #pragma unroll
            for (int off = 32; off; off >>= 1) ssum += __shfl_xor(ssum, off, 64);
            if (t < MEMN) lprobs[t] = e / ssum;
        }
        __syncthreads();
        // ---- response[d=t]: 4 accumulators over 50 rows ----
        {
            float r0 = 0.f, r1 = 0.f, r2 = 0.f, r3 = 0.f;
            #pragma unroll
            for (int k = 0; k < 48; k += 4) {
                r0 += lprobs[k]     * lout[k][t];
                r1 += lprobs[k + 1] * lout[k + 1][t];
                r2 += lprobs[k + 2] * lout[k + 2][t];
                r3 += lprobs[k + 3] * lout[k + 3][t];
            }
            r0 += lprobs[48] * lout[48][t];
            r1 += lprobs[49] * lout[49][t];
            lresp[t] = (r0 + r1) + (r2 + r3);
        }
        __syncthreads();
        // ---- state update: 4 accumulators over 128 k (HwT coalesced) ----
        {
            float a0 = Hb[t] + lstate[t], a1 = 0.f, a2 = 0.f, a3 = 0.f;
            #pragma unroll 8
            for (int k = 0; k < EMBED; k += 4) {
                a0 += lresp[k]     * HwT[(k)     * EMBED + t];
                a1 += lresp[k + 1] * HwT[(k + 1) * EMBED + t];
                a2 += lresp[k + 2] * HwT[(k + 2) * EMBED + t];
                a3 += lresp[k + 3] * HwT[(k + 3) * EMBED + t];
            }
            float ns = (a0 + a1) + (a2 + a3);
            lstate[t] = ns;   // own slot; barrier below orders vs next hop's reads
        }
        __syncthreads();
    }
    stateb[bn * EMBED + t] = __float2bfloat16(lstate[t]);
}

// ---- Kernel 3 (R2-exact): MFMA GEMM ----
__global__ __launch_bounds__(256) void k_out(const __hip_bfloat16* __restrict__ stateb,
                                             const float* __restrict__ outw,
                                             float* __restrict__ out) {
    __shared__ __align__(16) __hip_bfloat16 Alds[BN][EMBED + 8];
    __shared__ __align__(16) __hip_bfloat16 Blds[NV][EMBED + 8];
    int t = threadIdx.x;
    int vbase = blockIdx.x * NV;

    #pragma unroll
    for (int i = 0; i < 10; ++i) {
        int e = t + i * 256;
        int row = e >> 4, c8 = (e & 15) << 3;
        *(int4*)&Alds[row][c8] = *(const int4*)&stateb[row * EMBED + c8];
    }
    #pragma unroll
    for (int i = 0; i < 8; ++i) {
        int e = t + i * 256;
        int row = e >> 5, c4 = (e & 31) << 2;
        float4 w = *(const float4*)&outw[(size_t)(vbase + row) * EMBED + c4];
        short4 p;
        p.x = f2bf(w.x); p.y = f2bf(w.y); p.z = f2bf(w.z); p.w = f2bf(w.w);
        *(short4*)&Blds[row][c4] = p;
    }
    __syncthreads();

    int wv = t >> 6;
    int l = t & 63;
    int col16 = l & 15;
    int kg = l >> 4;

    v8s bfrag[4];
    #pragma unroll
    for (int k4 = 0; k4 < 4; ++k4)
        bfrag[k4] = *(v8s*)&Blds[(wv << 4) + col16][k4 * 32 + kg * 8];

    v4f acc[10];
    #pragma unroll
    for (int m = 0; m < 10; ++m) acc[m] = (v4f){0.f, 0.f, 0.f, 0.f};

    #pragma unroll
    for (int k4 = 0; k4 < 4; ++k4) {
        #pragma unroll
        for (int m = 0; m < 10; ++m) {
            v8s af = *(v8s*)&Alds[m * 16 + col16][k4 * 32 + kg * 8];
            acc[m] = __builtin_amdgcn_mfma_f32_16x16x32_bf16(af, bfrag[k4], acc[m], 0, 0, 0);
        }
    }

    int colg = vbase + (wv << 4) + col16;
    #pragma unroll
    for (int m = 0; m < 10; ++m) {
        #pragma unroll
        for (int i = 0; i < 4; ++i) {
            out[(size_t)(m * 16 + kg * 4 + i) * VOCAB + colg] = acc[m][i];
        }
    }
}

extern "C" void kernel_launch(void* const* d_in, const int* in_sizes, int n_in,
                              void* d_out, int out_size, void* d_ws, size_t ws_size,
                              hipStream_t stream) {
    const int*   ctx_query = (const int*)  d_in[0];
    const int*   story     = (const int*)  d_in[1];
    const float* A_w       = (const float*)d_in[2];
    const float* C_w       = (const float*)d_in[3];
    const float* B_w       = (const float*)d_in[4];
    const float* H_w       = (const float*)d_in[5];
    const float* H_b       = (const float*)d_in[6];
    const float* out_w     = (const float*)d_in[7];
    const float* TA        = (const float*)d_in[8];
    const float* TC        = (const float*)d_in[9];
    float* out = (float*)d_out;

    float* ws    = (float*)d_ws;
    float* state = ws;                                   // 160*128 f32
    float* memb  = state + BN * EMBED;                   // 16*50*128
    float* outb  = memb + BATCH * MEMN * EMBED;          // 16*50*128
    float* HwT   = outb + BATCH * MEMN * EMBED;          // 128*128
    __hip_bfloat16* stateb = (__hip_bfloat16*)(HwT + EMBED * EMBED);  // 160*128 bf16

    k_embed<<<BN + BATCH * MEMN + EMBED, EMBED, 0, stream>>>(
        ctx_query, story, B_w, A_w, C_w, TA, TC, H_w, state, memb, outb, HwT);
    k_hops<<<BN, EMBED, 0, stream>>>(memb, outb, HwT, H_b, state, stateb);
    k_out<<<VOCAB / NV, 256, 0, stream>>>(stateb, out_w, out);
}